// Round 7
// baseline (1434.908 us; speedup 1.0000x reference)
//
#include <hip/hip_runtime.h>

// Sinkhorn divergence, 512 independent 256-point problems, 24 annealing steps.
// Round 7: single-pass shifted logsumexp, shift predicted PER-ROW from the
// previous step's argmax column. The running max packs the column index into
// its low 8 mantissa bits (v_and_or_b32), so argmax tracking is ~1 extra
// instr/matrix/column. Next-step shift:
//   SH' = LA2 + rho*(M - LA2) + dpot_{j*}*inv'    (rho = eps_prev/eps)
// where dpot_{j*} is the potential change AT THE ARGMAX COLUMN, read from a
// per-column LDS table written each epilogue. Since
//   arg'_{j*} = LA2 + rho*(arg_{j*}-LA2) + dpot_{j*}*inv' = SH' (+-0.01),
// the sum always contains a term ~2^0: underflow impossible. Overflow (a
// different column's potential rising >120/inv above the old argmax's) is
// rare and handled by a barrier-free exact re-sum using the tracked max.
// Step 0: SH = LA2 exactly bounds the max (C <= diameter^2 = eps0).
// Structure: 512 threads, column halves (h=tid>>8), rows duplicated x2,
// conflict-free float4 LDS layout, 3 barriers/step, no per-step shuffles.

constexpr int   N       = 256;   // points per cloud
constexpr int   NPROB   = 512;   // B*S*NR
constexpr int   NRDIM   = 64;
constexpr float DT_F    = 0.001f;
constexpr float EPS_MIN = 1e-4f; // BLUR^P
constexpr int   NSTEPS  = 24;
constexpr float LOG2E   = 1.4426950408889634f;
constexpr float LN2     = 0.6931471805599453f;
constexpr int   NTH     = 512;   // threads per block
constexpr int   CPH     = 128;   // columns per half
constexpr float LA2     = -8.0f; // log2(1/256)

__device__ __forceinline__ float pkmax(float e, int j) {
    // keep e's high mantissa, stash column index in low 8 bits (<=0.002 err)
    unsigned u = (__float_as_uint(e) & 0xFFFFFF00u) | (unsigned)j;
    return __uint_as_float(u);
}

extern "C" __global__ void __launch_bounds__(NTH, 4)
sinkhorn_div_kernel(const float* __restrict__ syn,
                    const float* __restrict__ obs,
                    float* __restrict__ divs)
{
    const int p   = blockIdx.x;          // ((b*S + s)*NR + r)
    const int r   = p & (NRDIM - 1);
    const int bs  = p >> 6;
    const int tid = threadIdx.x;
    const int row = tid & (N - 1);       // row index i (duplicated x2)
    const int h   = tid >> 8;            // column half 0..1

    __shared__ float4 ya[N];             // (Hxy, Hyy, y_j*inv, 0)
    __shared__ float4 xa[N];             // (Hyx, Hxx, x_j*inv, 0)
    __shared__ float4 ssh[NTH];          // per-thread partial sums
    __shared__ float4 msh[NTH];          // per-thread partial packed maxima
    __shared__ float4 dsh[N];            // per-column pot changes (df,dg,dpx,dpy)
    __shared__ float  redA[32];

    const size_t base = (size_t)bs * N * NRDIM + r;
    const float xi = obs[base + (size_t)row * NRDIM];   // x cloud = obs
    const float yi = syn[base + (size_t)row * NRDIM];   // y cloud = syn

    // ---- block reductions: diameter (max/min) + all-zero mask sums ----
    float hi = fmaxf(xi, yi), lo = fminf(xi, yi);
    float ax = fabsf(xi),     ay = fabsf(yi);
    #pragma unroll
    for (int off = 32; off > 0; off >>= 1) {
        hi  = fmaxf(hi, __shfl_down(hi, off, 64));
        lo  = fminf(lo, __shfl_down(lo, off, 64));
        ax += __shfl_down(ax, off, 64);
        ay += __shfl_down(ay, off, 64);
    }
    const int wave = tid >> 6;           // 0..7
    if ((tid & 63) == 0) {
        redA[wave * 4 + 0] = hi;  redA[wave * 4 + 1] = lo;
        redA[wave * 4 + 2] = ax;  redA[wave * 4 + 3] = ay;
    }
    __syncthreads();
    float vmax = -3.4e38f, vmin = 3.4e38f, sax = 0.0f, say = 0.0f;
    #pragma unroll
    for (int w = 0; w < 8; ++w) {
        vmax = fmaxf(vmax, redA[w * 4 + 0]);
        vmin = fminf(vmin, redA[w * 4 + 1]);
        sax += redA[w * 4 + 2];
        say += redA[w * 4 + 3];
    }

    const float tspread  = 255.0f * DT_F;
    const float diameter = fmaxf(tspread, vmax - vmin);
    float eps_raw = diameter * diameter;              // eps0 = diameter^2

    const float ti    = (float)row * DT_F;
    const float selfx = 0.5f * (ti * ti + xi * xi);
    const float selfy = 0.5f * (ti * ti + yi * yi);

    float f = 0.0f, g = 0.0f, px = 0.0f, py = 0.0f;
    float SH0 = LA2, SH1 = LA2, SH2 = LA2, SH3 = LA2;
    float mr0 = 0.f, mr1 = 0.f, mr2 = 0.f, mr3 = 0.f;  // prev packed rel-max
    float eps_prev = 1.0f;

    const int j0 = h * CPH;

    for (int step = 0; step < NSTEPS; ++step) {
        const float eps = fmaxf(eps_raw, EPS_MIN);
        const float inv = LOG2E / eps;

        // ---- per-row shift prediction from previous argmax column ----
        if (step > 0) {
            const float rho = eps_prev / eps;
            const int jj0 = __float_as_uint(mr0) & 0xFF;
            const int jj1 = __float_as_uint(mr1) & 0xFF;
            const int jj2 = __float_as_uint(mr2) & 0xFF;
            const int jj3 = __float_as_uint(mr3) & 0xFF;
            const float dd0 = dsh[jj0].y;   // xy: cols carry g
            const float dd1 = dsh[jj1].x;   // yx: cols carry f
            const float dd2 = dsh[jj2].z;   // xx: cols carry px
            const float dd3 = dsh[jj3].w;   // yy: cols carry py
            const float M0 = SH0 + mr0, M1 = SH1 + mr1;
            const float M2 = SH2 + mr2, M3 = SH3 + mr3;
            SH0 = fmaf(rho, M0 - LA2, LA2) + dd0 * inv;
            SH1 = fmaf(rho, M1 - LA2, LA2) + dd1 * inv;
            SH2 = fmaf(rho, M2 - LA2, LA2) + dd2 * inv;
            SH3 = fmaf(rho, M3 - LA2, LA2) + dd3 * inv;
        }

        // ---- prologue: half 0 provides column j = row of all arrays ----
        if (h == 0) {
            const float Hxy = fmaf(g  - selfy, inv, LA2);
            const float Hyy = fmaf(py - selfy, inv, LA2);
            const float Hyx = fmaf(f  - selfx, inv, LA2);
            const float Hxx = fmaf(px - selfx, inv, LA2);
            ya[row] = make_float4(Hxy, Hyy, yi * inv, 0.0f);
            xa[row] = make_float4(Hyx, Hxx, xi * inv, 0.0f);
        }
        __syncthreads();   // S1

        const float a = ti * DT_F * inv;      // t-term increment per column

        // ---- single pass: shifted sums + packed argmax over this half ----
        float s0 = 0.f, s1 = 0.f, s2 = 0.f, s3 = 0.f;
        float mp0 = -3.4e38f, mp1 = -3.4e38f, mp2 = -3.4e38f, mp3 = -3.4e38f;
        {
            const float rbase = a * (float)j0;
            float r0 = rbase - SH0, r1 = rbase - SH1;
            float r2 = rbase - SH2, r3 = rbase - SH3;
            #pragma unroll 4
            for (int j = j0; j < j0 + CPH; j += 2) {
                const float4 yA0 = ya[j];
                const float4 xA0 = xa[j];
                const float4 yA1 = ya[j + 1];
                const float4 xA1 = xa[j + 1];
                // column j
                const float e00 = fmaf(xi, yA0.z, yA0.x + r0);   // xy
                const float e30 = fmaf(yi, yA0.z, yA0.y + r3);   // yy
                const float e10 = fmaf(yi, xA0.z, xA0.x + r1);   // yx
                const float e20 = fmaf(xi, xA0.z, xA0.y + r2);   // xx
                r0 += a; r1 += a; r2 += a; r3 += a;
                // column j+1
                const float e01 = fmaf(xi, yA1.z, yA1.x + r0);
                const float e31 = fmaf(yi, yA1.z, yA1.y + r3);
                const float e11 = fmaf(yi, xA1.z, xA1.x + r1);
                const float e21 = fmaf(xi, xA1.z, xA1.y + r2);
                r0 += a; r1 += a; r2 += a; r3 += a;
                // packed max (v_max3 pattern) + sums
                mp0 = fmaxf(mp0, fmaxf(pkmax(e00, j), pkmax(e01, j + 1)));
                mp1 = fmaxf(mp1, fmaxf(pkmax(e10, j), pkmax(e11, j + 1)));
                mp2 = fmaxf(mp2, fmaxf(pkmax(e20, j), pkmax(e21, j + 1)));
                mp3 = fmaxf(mp3, fmaxf(pkmax(e30, j), pkmax(e31, j + 1)));
                s0 += __builtin_amdgcn_exp2f(e00) + __builtin_amdgcn_exp2f(e01);
                s1 += __builtin_amdgcn_exp2f(e10) + __builtin_amdgcn_exp2f(e11);
                s2 += __builtin_amdgcn_exp2f(e20) + __builtin_amdgcn_exp2f(e21);
                s3 += __builtin_amdgcn_exp2f(e30) + __builtin_amdgcn_exp2f(e31);
            }
        }
        ssh[tid] = make_float4(s0, s1, s2, s3);
        msh[tid] = make_float4(mp0, mp1, mp2, mp3);
        __syncthreads();   // S2

        // ---- combine halves (fixed order -> deterministic) ----
        float S0, S1, S2, S3;
        {
            const float4 sa = ssh[row];
            const float4 sb = ssh[row + 256];
            S0 = sa.x + sb.x;  S1 = sa.y + sb.y;
            S2 = sa.z + sb.z;  S3 = sa.w + sb.w;
            const float4 ma = msh[row];
            const float4 mb = msh[row + 256];
            mr0 = fmaxf(ma.x, mb.x);  mr1 = fmaxf(ma.y, mb.y);
            mr2 = fmaxf(ma.z, mb.z);  mr3 = fmaxf(ma.w, mb.w);
        }

        // base for L: L = b + log2(S)
        float b0 = SH0, b1 = SH1, b2 = SH2, b3 = SH3;

        // ---- rare overflow redo: barrier-free exact re-sum vs tracked max ----
        const bool bad = !(S0 <= 3.0e38f) || !(S1 <= 3.0e38f)
                      || !(S2 <= 3.0e38f) || !(S3 <= 3.0e38f);
        if (__builtin_expect(bad, 0)) {
            b0 = SH0 + mr0; b1 = SH1 + mr1; b2 = SH2 + mr2; b3 = SH3 + mr3;
            S0 = S1 = S2 = S3 = 0.0f;
            float r0 = -b0, r1 = -b1, r2 = -b2, r3 = -b3;
            for (int j = 0; j < N; ++j) {
                const float4 yA = ya[j];
                const float4 xA = xa[j];
                S0 += __builtin_amdgcn_exp2f(fmaf(xi, yA.z, yA.x + r0));
                S3 += __builtin_amdgcn_exp2f(fmaf(yi, yA.z, yA.y + r3));
                S1 += __builtin_amdgcn_exp2f(fmaf(yi, xA.z, xA.x + r1));
                S2 += __builtin_amdgcn_exp2f(fmaf(xi, xA.z, xA.y + r2));
                r0 += a; r1 += a; r2 += a; r3 += a;
            }
        }

        // ---- epilogue: exact logsumexp (valid for any shift) ----
        const float L0 = b0 + __builtin_amdgcn_logf(S0);   // v_log_f32 = log2
        const float L1 = b1 + __builtin_amdgcn_logf(S1);
        const float L2 = b2 + __builtin_amdgcn_logf(S2);
        const float L3 = b3 + __builtin_amdgcn_logf(S3);
        const float el2 = eps * LN2;
        const float fn  = selfx - el2 * L0;
        const float gn  = selfy - el2 * L1;
        const float pxn = 0.5f * (px + (selfx - el2 * L2));
        const float pyn = 0.5f * (py + (selfy - el2 * L3));
        const float ddf = fn - f, ddg = gn - g;
        const float ddpx = pxn - px, ddpy = pyn - py;
        f = fn; g = gn; px = pxn; py = pyn;

        // ---- per-column potential changes for next step's shift ----
        if (h == 0) dsh[row] = make_float4(ddf, ddg, ddpx, ddpy);
        __syncthreads();   // S3 (orders dsh + ya/xa for next iteration)

        eps_prev = eps;
        eps_raw *= 0.25f;
    }

    // ---- divergence: (1/n) * sum_i [(f-px)+(g-py)], rows duplicated x2 ----
    float contrib = (f - px) + (g - py);
    #pragma unroll
    for (int off = 32; off > 0; off >>= 1)
        contrib += __shfl_down(contrib, off, 64);
    __syncthreads();                      // redA reuse
    if ((tid & 63) == 0) redA[wave] = contrib;
    __syncthreads();
    if (tid == 0) {
        float total = 0.0f;
        #pragma unroll
        for (int w = 0; w < 8; ++w) total += redA[w];
        total *= (1.0f / (float)(2 * N));             // x2 duplication
        const bool masked_out = (sax == 0.0f) && (say == 0.0f);
        divs[p] = masked_out ? 0.0f : total;
    }
}

extern "C" __global__ void __launch_bounds__(256)
reduce_out_kernel(const float* __restrict__ divs, float* __restrict__ out)
{
    const int b   = blockIdx.x;
    const int tid = threadIdx.x;
    __shared__ float red[4];
    float v = divs[b * 256 + tid];        // 256 = S*NR problems per batch
    #pragma unroll
    for (int off = 32; off > 0; off >>= 1)
        v += __shfl_down(v, off, 64);
    if ((tid & 63) == 0) red[tid >> 6] = v;
    __syncthreads();
    if (tid == 0) out[b] = red[0] + red[1] + red[2] + red[3];
}

extern "C" void kernel_launch(void* const* d_in, const int* in_sizes, int n_in,
                              void* d_out, int out_size, void* d_ws, size_t ws_size,
                              hipStream_t stream) {
    const float* syn = (const float*)d_in[0];   // syn_data
    const float* obs = (const float*)d_in[1];   // obs_data
    float* divs = (float*)d_ws;                 // 512 floats scratch

    sinkhorn_div_kernel<<<NPROB, NTH, 0, stream>>>(syn, obs, divs);
    reduce_out_kernel<<<2, 256, 0, stream>>>(divs, (float*)d_out);
}